// Round 1
// 790.351 us; speedup vs baseline: 1.5991x; 1.5991x over previous
//
#include <hip/hip_runtime.h>
#include <math.h>
#include <cstddef>
#include <cstdint>

#define B_ 8
#define S_ 4096
#define D_ 256

typedef __attribute__((ext_vector_type(8))) short short8v;   // 8 bf16 (4 VGPR)
typedef __attribute__((ext_vector_type(4))) short short4v;   // 4 bf16 (8 B)
typedef __attribute__((ext_vector_type(4))) float float4v;   // MFMA C/D

// float -> bf16 (RNE) and back, on bit patterns
__device__ __forceinline__ unsigned short f2bf(float f) {
  unsigned u = __float_as_uint(f);
  return (unsigned short)((u + 0x7FFF + ((u >> 16) & 1)) >> 16);
}
__device__ __forceinline__ float bf2f(unsigned short h) {
  return __uint_as_float((unsigned)h << 16);
}

// ---------------------------------------------------------------------------
// fp32 GEMM (used for Wo): C[M,256] = A @ W + bias, natural layout.
// ---------------------------------------------------------------------------
__global__ __launch_bounds__(256, 2) void gemm_bias_kernel(
    const float* __restrict__ A, const float* __restrict__ W,
    const float* __restrict__ bias, float* __restrict__ C) {
  __shared__ __align__(16) float sA[32 * 68];
  __shared__ __align__(16) float sW[32 * 260];
  const int t  = threadIdx.x;
  const int tx = t & 31;
  const int ty = t >> 5;
  const size_t m0 = (size_t)blockIdx.x * 64;

  float acc[8][8] = {};

  for (int kc = 0; kc < 8; ++kc) {
    const int k0 = kc << 5;
    __syncthreads();
#pragma unroll
    for (int l = 0; l < 2; ++l) {
      const int idx = t + (l << 8);
      const int r = idx >> 3, cf = (idx & 7) << 2;
      const float4 a4 = *(const float4*)(A + (m0 + r) * 256 + k0 + cf);
      sA[(cf + 0) * 68 + r] = a4.x;
      sA[(cf + 1) * 68 + r] = a4.y;
      sA[(cf + 2) * 68 + r] = a4.z;
      sA[(cf + 3) * 68 + r] = a4.w;
    }
#pragma unroll
    for (int l = 0; l < 8; ++l) {
      const int idx = t + (l << 8);
      const int kr = idx >> 6, nc = (idx & 63) << 2;
      *(float4*)&sW[kr * 260 + nc] =
          *(const float4*)(W + (size_t)(k0 + kr) * 256 + nc);
    }
    __syncthreads();
#pragma unroll
    for (int kk = 0; kk < 32; ++kk) {
      const float4 a0 = *(const float4*)&sA[kk * 68 + (ty << 3)];
      const float4 a1 = *(const float4*)&sA[kk * 68 + (ty << 3) + 4];
      const float4 b0 = *(const float4*)&sW[kk * 260 + (tx << 2)];
      const float4 b1 = *(const float4*)&sW[kk * 260 + 128 + (tx << 2)];
      const float av[8] = {a0.x, a0.y, a0.z, a0.w, a1.x, a1.y, a1.z, a1.w};
      const float bv[8] = {b0.x, b0.y, b0.z, b0.w, b1.x, b1.y, b1.z, b1.w};
#pragma unroll
      for (int i = 0; i < 8; ++i)
#pragma unroll
        for (int c = 0; c < 8; ++c) acc[i][c] += av[i] * bv[c];
    }
  }

  const float4 bb0 = *(const float4*)(bias + (tx << 2));
  const float4 bb1 = *(const float4*)(bias + 128 + (tx << 2));
#pragma unroll
  for (int i = 0; i < 8; ++i) {
    float4 o0, o1;
    o0.x = acc[i][0] + bb0.x; o0.y = acc[i][1] + bb0.y;
    o0.z = acc[i][2] + bb0.z; o0.w = acc[i][3] + bb0.w;
    o1.x = acc[i][4] + bb1.x; o1.y = acc[i][5] + bb1.y;
    o1.z = acc[i][6] + bb1.z; o1.w = acc[i][7] + bb1.w;
    float* cp = C + (m0 + (ty << 3) + i) * 256;
    *(float4*)(cp + (tx << 2)) = o0;
    *(float4*)(cp + 128 + (tx << 2)) = o1;
  }
}

// ---------------------------------------------------------------------------
// Projection GEMM -> split-bf16 NATURAL output [b][s][d]: yh + yl (hi/lo).
// scale folded in before the split (Q uses 1/16, K uses 1).
// ---------------------------------------------------------------------------
__global__ __launch_bounds__(256, 2) void proj_split_nat_kernel(
    const float* __restrict__ A, const float* __restrict__ W,
    const float* __restrict__ bias, short* __restrict__ outh,
    short* __restrict__ outl, float scale) {
  __shared__ __align__(16) float sA[32 * 68];
  __shared__ __align__(16) float sW[32 * 260];
  const int t  = threadIdx.x;
  const int tx = t & 31;
  const int ty = t >> 5;
  const size_t m0 = (size_t)blockIdx.x * 64;

  float acc[8][8] = {};

  for (int kc = 0; kc < 8; ++kc) {
    const int k0 = kc << 5;
    __syncthreads();
#pragma unroll
    for (int l = 0; l < 2; ++l) {
      const int idx = t + (l << 8);
      const int r = idx >> 3, cf = (idx & 7) << 2;
      const float4 a4 = *(const float4*)(A + (m0 + r) * 256 + k0 + cf);
      sA[(cf + 0) * 68 + r] = a4.x;
      sA[(cf + 1) * 68 + r] = a4.y;
      sA[(cf + 2) * 68 + r] = a4.z;
      sA[(cf + 3) * 68 + r] = a4.w;
    }
#pragma unroll
    for (int l = 0; l < 8; ++l) {
      const int idx = t + (l << 8);
      const int kr = idx >> 6, nc = (idx & 63) << 2;
      *(float4*)&sW[kr * 260 + nc] =
          *(const float4*)(W + (size_t)(k0 + kr) * 256 + nc);
    }
    __syncthreads();
#pragma unroll
    for (int kk = 0; kk < 32; ++kk) {
      const float4 a0 = *(const float4*)&sA[kk * 68 + (ty << 3)];
      const float4 a1 = *(const float4*)&sA[kk * 68 + (ty << 3) + 4];
      const float4 b0 = *(const float4*)&sW[kk * 260 + (tx << 2)];
      const float4 b1 = *(const float4*)&sW[kk * 260 + 128 + (tx << 2)];
      const float av[8] = {a0.x, a0.y, a0.z, a0.w, a1.x, a1.y, a1.z, a1.w};
      const float bv[8] = {b0.x, b0.y, b0.z, b0.w, b1.x, b1.y, b1.z, b1.w};
#pragma unroll
      for (int i = 0; i < 8; ++i)
#pragma unroll
        for (int c = 0; c < 8; ++c) acc[i][c] += av[i] * bv[c];
    }
  }

  const float4 bb0 = *(const float4*)(bias + (tx << 2));
  const float4 bb1 = *(const float4*)(bias + 128 + (tx << 2));
  const float bb0v[4] = {bb0.x, bb0.y, bb0.z, bb0.w};
  const float bb1v[4] = {bb1.x, bb1.y, bb1.z, bb1.w};
#pragma unroll
  for (int i = 0; i < 8; ++i) {
    const size_t ro = (m0 + (ty << 3) + i) * 256;
    short4v h0, l0, h1, l1;
#pragma unroll
    for (int c = 0; c < 4; ++c) {
      const float y0 = (acc[i][c] + bb0v[c]) * scale;
      const unsigned short hh0 = f2bf(y0);
      h0[c] = (short)hh0; l0[c] = (short)f2bf(y0 - bf2f(hh0));
      const float y1 = (acc[i][4 + c] + bb1v[c]) * scale;
      const unsigned short hh1 = f2bf(y1);
      h1[c] = (short)hh1; l1[c] = (short)f2bf(y1 - bf2f(hh1));
    }
    *(short4v*)(outh + ro + (tx << 2)) = h0;
    *(short4v*)(outl + ro + (tx << 2)) = l0;
    *(short4v*)(outh + ro + 128 + (tx << 2)) = h1;
    *(short4v*)(outl + ro + 128 + (tx << 2)) = l1;
  }
}

// ---------------------------------------------------------------------------
// V projection -> split-bf16 TRANSPOSED output [b][d][s]: vth + vtl.
// ---------------------------------------------------------------------------
__global__ __launch_bounds__(256, 2) void proj_split_t_kernel(
    const float* __restrict__ A, const float* __restrict__ W,
    const float* __restrict__ bias, short* __restrict__ vth,
    short* __restrict__ vtl) {
  __shared__ __align__(16) float sA[32 * 68];
  __shared__ __align__(16) float sW[32 * 260];
  const int t  = threadIdx.x;
  const int tx = t & 31;
  const int ty = t >> 5;
  const size_t m0 = (size_t)blockIdx.x * 64;

  float acc[8][8] = {};

  for (int kc = 0; kc < 8; ++kc) {
    const int k0 = kc << 5;
    __syncthreads();
#pragma unroll
    for (int l = 0; l < 2; ++l) {
      const int idx = t + (l << 8);
      const int r = idx >> 3, cf = (idx & 7) << 2;
      const float4 a4 = *(const float4*)(A + (m0 + r) * 256 + k0 + cf);
      sA[(cf + 0) * 68 + r] = a4.x;
      sA[(cf + 1) * 68 + r] = a4.y;
      sA[(cf + 2) * 68 + r] = a4.z;
      sA[(cf + 3) * 68 + r] = a4.w;
    }
#pragma unroll
    for (int l = 0; l < 8; ++l) {
      const int idx = t + (l << 8);
      const int kr = idx >> 6, nc = (idx & 63) << 2;
      *(float4*)&sW[kr * 260 + nc] =
          *(const float4*)(W + (size_t)(k0 + kr) * 256 + nc);
    }
    __syncthreads();
#pragma unroll
    for (int kk = 0; kk < 32; ++kk) {
      const float4 a0 = *(const float4*)&sA[kk * 68 + (ty << 3)];
      const float4 a1 = *(const float4*)&sA[kk * 68 + (ty << 3) + 4];
      const float4 b0 = *(const float4*)&sW[kk * 260 + (tx << 2)];
      const float4 b1 = *(const float4*)&sW[kk * 260 + 128 + (tx << 2)];
      const float av[8] = {a0.x, a0.y, a0.z, a0.w, a1.x, a1.y, a1.z, a1.w};
      const float bv[8] = {b0.x, b0.y, b0.z, b0.w, b1.x, b1.y, b1.z, b1.w};
#pragma unroll
      for (int i = 0; i < 8; ++i)
#pragma unroll
        for (int c = 0; c < 8; ++c) acc[i][c] += av[i] * bv[c];
    }
  }

  const size_t bD = (size_t)(m0 >> 12) * (D_ * (size_t)S_);
  const int s0r = (int)(m0 & 4095) + (ty << 3);
#pragma unroll
  for (int c = 0; c < 8; ++c) {
    const int n = (c < 4) ? ((tx << 2) + c) : (128 + (tx << 2) + (c - 4));
    const float bn = bias[n];
    short8v h8, l8;
#pragma unroll
    for (int i = 0; i < 8; ++i) {
      const float y = acc[i][c] + bn;
      const unsigned short hh = f2bf(y);
      h8[i] = (short)hh; l8[i] = (short)f2bf(y - bf2f(hh));
    }
    *(short8v*)(vth + bD + (size_t)n * S_ + s0r) = h8;
    *(short8v*)(vtl + bD + (size_t)n * S_ + s0r) = l8;
  }
}

// ---------------------------------------------------------------------------
// MFMA flash attention, split-bf16 (3-term: Ah*Bh + Ah*Bl + Al*Bh).
// NEW STRUCTURE (this round):
//   - 8 waves / 512 threads per block, 128 q-rows per block.
//     grid (32, 8) = 256 blocks = exactly 1 block/CU; 2 waves/SIMD.
//     Each staged K/V tile now feeds 2x the MFMA work (halved staging +
//     barrier cost per FLOP vs the 4-wave version).
//   - T14 register-prefetch pipelining: V(jt) global loads are issued
//     BEFORE the QK phase and written to LDS after it; K(jt+1) loads are
//     issued before the PV phase and written at the top of the next
//     iteration. Global-load latency hides under ~1000+ cycles of
//     MFMA+softmax instead of sitting between back-to-back barriers.
// Fragment layouts, split-bf16 math, LDS bank patterns unchanged.
// ---------------------------------------------------------------------------
__global__ __launch_bounds__(512, 2) void flash_attn_mfma(
    const short* __restrict__ qh, const short* __restrict__ ql,
    const short* __restrict__ kh, const short* __restrict__ kl,
    const short* __restrict__ vth, const short* __restrict__ vtl,
    float* __restrict__ ctx) {
  // union buffer: K-phase Kh[32*264]@0, Kl@8448 | V-phase Vth[256*40]@0, Vtl@10240
  __shared__ __align__(16) short sKV[20480];   // 40 KB
  __shared__ unsigned int sP[8][16][36];       // 18 KB, per-wave P tiles

  const int t    = threadIdx.x;
  const int w    = t >> 6;          // 0..7
  const int lane = t & 63;
  const int m    = lane & 15;
  const int quad = lane >> 4;
  const int q0   = blockIdx.x * 128;
  const int b    = blockIdx.y;
  const size_t sd = (size_t)b * (S_ * (size_t)D_);
  const size_t bD = (size_t)b * (D_ * (size_t)S_);

  // Q A-frags, resident in registers for the whole kernel
  short8v aqh[8], aql[8];
  {
    const size_t row = sd + (size_t)(q0 + 16 * w + m) * D_;
#pragma unroll
    for (int kk = 0; kk < 8; ++kk) {
      const size_t off = row + kk * 32 + quad * 8;
      aqh[kk] = *(const short8v*)(qh + off);
      aql[kk] = *(const short8v*)(ql + off);
    }
  }

  float4v acc[16];
#pragma unroll
  for (int dt = 0; dt < 16; ++dt) acc[dt] = (float4v){0.f, 0.f, 0.f, 0.f};
  float m_i[4], l_i[4];
#pragma unroll
  for (int r = 0; r < 4; ++r) { m_i[r] = -INFINITY; l_i[r] = 0.f; }

  // ---- staging addresses (512 threads) ----
  // K tile [32 j][256 d]: thread covers rows kr0 and 16+kr0, 8-short chunk kc0
  const int kr0 = t >> 5;            // 0..15
  const int kc0 = (t & 31) << 3;     // 0..248
  // V tile [256 d][32 j]: thread covers row vd, chunks vjh and vjh+8
  const int vd  = t >> 1;            // 0..255
  const int vjh = (t & 1) << 4;      // 0 or 16

  // prefetch registers (named scalars -> stay in VGPRs, rule: no dyn index)
  short8v rKh0, rKh1, rKl0, rKl1;
  short8v rVh0, rVh1, rVl0, rVl1;

  // prologue: issue K(0) loads
  {
    const size_t g0 = sd + (size_t)kr0 * D_ + kc0;
    const size_t g1 = sd + (size_t)(16 + kr0) * D_ + kc0;
    rKh0 = *(const short8v*)(kh + g0);
    rKh1 = *(const short8v*)(kh + g1);
    rKl0 = *(const short8v*)(kl + g0);
    rKl1 = *(const short8v*)(kl + g1);
  }

  for (int jt = 0; jt < 128; ++jt) {
    const int j0 = jt << 5;

    __syncthreads();  // (a) prior PV reads of sKV done
    // ---- write prefetched K(jt) regs -> LDS [32 j][264 pad] ----
    *(short8v*)&sKV[kr0 * 264 + kc0]               = rKh0;
    *(short8v*)&sKV[(16 + kr0) * 264 + kc0]        = rKh1;
    *(short8v*)&sKV[8448 + kr0 * 264 + kc0]        = rKl0;
    *(short8v*)&sKV[8448 + (16 + kr0) * 264 + kc0] = rKl1;
    // ---- issue V(jt) global loads (consumed after QK phase) ----
    {
      const size_t g = bD + (size_t)vd * S_ + j0 + vjh;
      rVh0 = *(const short8v*)(vth + g);
      rVh1 = *(const short8v*)(vth + g + 8);
      rVl0 = *(const short8v*)(vtl + g);
      rVl1 = *(const short8v*)(vtl + g + 8);
    }
    __syncthreads();  // (b) K tile visible

    // ---- scores: 16(q) x 32(j), D in 8 K-steps of 32 ----
    float4v s0 = (float4v){0.f, 0.f, 0.f, 0.f};
    float4v s1 = (float4v){0.f, 0.f, 0.f, 0.f};
#pragma unroll
    for (int kk = 0; kk < 8; ++kk) {
      const int co = kk * 32 + quad * 8;
      const short8v bh0 = *(const short8v*)&sKV[m * 264 + co];
      const short8v bl0 = *(const short8v*)&sKV[8448 + m * 264 + co];
      const short8v bh1 = *(const short8v*)&sKV[(16 + m) * 264 + co];
      const short8v bl1 = *(const short8v*)&sKV[8448 + (16 + m) * 264 + co];
      s0 = __builtin_amdgcn_mfma_f32_16x16x32_bf16(aqh[kk], bh0, s0, 0, 0, 0);
      s0 = __builtin_amdgcn_mfma_f32_16x16x32_bf16(aqh[kk], bl0, s0, 0, 0, 0);
      s0 = __builtin_amdgcn_mfma_f32_16x16x32_bf16(aql[kk], bh0, s0, 0, 0, 0);
      s1 = __builtin_amdgcn_mfma_f32_16x16x32_bf16(aqh[kk], bh1, s1, 0, 0, 0);
      s1 = __builtin_amdgcn_mfma_f32_16x16x32_bf16(aqh[kk], bl1, s1, 0, 0, 0);
      s1 = __builtin_amdgcn_mfma_f32_16x16x32_bf16(aql[kk], bh1, s1, 0, 0, 0);
    }

    // ---- online softmax (row r of this wave's tile = quad*4 + r) ----
    float alpha[4], pr0[4], pr1[4];
#pragma unroll
    for (int r = 0; r < 4; ++r) {
      float mx = fmaxf(s0[r], s1[r]);
      mx = fmaxf(mx, __shfl_xor(mx, 1, 64));
      mx = fmaxf(mx, __shfl_xor(mx, 2, 64));
      mx = fmaxf(mx, __shfl_xor(mx, 4, 64));
      mx = fmaxf(mx, __shfl_xor(mx, 8, 64));
      const float mnew = fmaxf(m_i[r], mx);
      alpha[r] = __expf(m_i[r] - mnew);
      m_i[r] = mnew;
      const float p0 = __expf(s0[r] - mnew);
      const float p1 = __expf(s1[r] - mnew);
      float rs = p0 + p1;
      rs += __shfl_xor(rs, 1, 64);
      rs += __shfl_xor(rs, 2, 64);
      rs += __shfl_xor(rs, 4, 64);
      rs += __shfl_xor(rs, 8, 64);
      l_i[r] = l_i[r] * alpha[r] + rs;
      pr0[r] = p0; pr1[r] = p1;
    }

    // ---- write split P to per-wave LDS (C-layout -> [row][j] packed) ----
#pragma unroll
    for (int r = 0; r < 4; ++r) {
      {
        const float p = pr0[r];
        const unsigned short hh = f2bf(p);
        const unsigned short ll = f2bf(p - bf2f(hh));
        sP[w][quad * 4 + r][m] = ((unsigned)hh << 16) | (unsigned)ll;
      }
      {
        const float p = pr1[r];
        const unsigned short hh = f2bf(p);
        const unsigned short ll = f2bf(p - bf2f(hh));
        sP[w][quad * 4 + r][16 + m] = ((unsigned)hh << 16) | (unsigned)ll;
      }
    }

    // ---- rescale ctx accumulators ----
#pragma unroll
    for (int dt = 0; dt < 16; ++dt)
#pragma unroll
      for (int r = 0; r < 4; ++r) acc[dt][r] *= alpha[r];

    __syncthreads();  // (c) all waves done reading K tile
    // ---- write prefetched V(jt) regs -> LDS [256 d][40 pad] ----
    *(short8v*)&sKV[vd * 40 + vjh]               = rVh0;
    *(short8v*)&sKV[vd * 40 + vjh + 8]           = rVh1;
    *(short8v*)&sKV[10240 + vd * 40 + vjh]       = rVl0;
    *(short8v*)&sKV[10240 + vd * 40 + vjh + 8]   = rVl1;
    // ---- issue K(jt+1) global loads (consumed at next (a)) ----
    if (jt < 127) {
      const int j0n = j0 + 32;
      const size_t g0 = sd + (size_t)(j0n + kr0) * D_ + kc0;
      const size_t g1 = sd + (size_t)(j0n + 16 + kr0) * D_ + kc0;
      rKh0 = *(const short8v*)(kh + g0);
      rKh1 = *(const short8v*)(kh + g1);
      rKl0 = *(const short8v*)(kl + g0);
      rKl1 = *(const short8v*)(kl + g1);
    }
    __syncthreads();  // (d) V tile visible

    // ---- P A-frag: read back in A-layout, unpack hi/lo ----
    short8v ph, pl;
    {
      const uint4 pa = *(const uint4*)&sP[w][m][quad * 8];
      const uint4 pb = *(const uint4*)&sP[w][m][quad * 8 + 4];
      ph[0] = (short)(pa.x >> 16); pl[0] = (short)(pa.x & 0xffff);
      ph[1] = (short)(pa.y >> 16); pl[1] = (short)(pa.y & 0xffff);
      ph[2] = (short)(pa.z >> 16); pl[2] = (short)(pa.z & 0xffff);
      ph[3] = (short)(pa.w >> 16); pl[3] = (short)(pa.w & 0xffff);
      ph[4] = (short)(pb.x >> 16); pl[4] = (short)(pb.x & 0xffff);
      ph[5] = (short)(pb.y >> 16); pl[5] = (short)(pb.y & 0xffff);
      ph[6] = (short)(pb.z >> 16); pl[6] = (short)(pb.z & 0xffff);
      ph[7] = (short)(pb.w >> 16); pl[7] = (short)(pb.w & 0xffff);
    }

    // ---- PV: ctx[16 q][256 d] += P[16 q][32 j] @ V[32 j][256 d] ----
#pragma unroll
    for (int dt = 0; dt < 16; ++dt) {
      const int vr = (dt * 16 + m) * 40 + quad * 8;
      const short8v bh = *(const short8v*)&sKV[vr];
      const short8v bl = *(const short8v*)&sKV[10240 + vr];
      acc[dt] = __builtin_amdgcn_mfma_f32_16x16x32_bf16(ph, bh, acc[dt], 0, 0, 0);
      acc[dt] = __builtin_amdgcn_mfma_f32_16x16x32_bf16(ph, bl, acc[dt], 0, 0, 0);
      acc[dt] = __builtin_amdgcn_mfma_f32_16x16x32_bf16(pl, bh, acc[dt], 0, 0, 0);
    }
  }

  // ---- finalize: divide by l, store ctx (C-layout scatter, 64B granules) ----
#pragma unroll
  for (int r = 0; r < 4; ++r) {
    const float inv = 1.0f / l_i[r];
    float* cp = ctx + sd + (size_t)(q0 + 16 * w + quad * 4 + r) * D_ + m;
#pragma unroll
    for (int dt = 0; dt < 16; ++dt) cp[dt * 16] = acc[dt][r] * inv;
  }
}

// ---------------------------------------------------------------------------
// w[row] = dot(logits[row,:], cv)
// ---------------------------------------------------------------------------
__global__ __launch_bounds__(256) void wdot_kernel(
    const float* __restrict__ logits, const float* __restrict__ cv,
    float* __restrict__ w) {
  const int t    = threadIdx.x;
  const int wave = t >> 6, lane = t & 63;
  const size_t row = (size_t)blockIdx.x * 4 + wave;
  const float4 l4 = *(const float4*)(logits + row * 256 + (lane << 2));
  const float4 c4 = *(const float4*)(cv + (lane << 2));
  float p = l4.x * c4.x + l4.y * c4.y + l4.z * c4.z + l4.w * c4.w;
#pragma unroll
  for (int off = 32; off > 0; off >>= 1) p += __shfl_down(p, off, 64);
  if (lane == 0) w[row] = p;
}

// ---------------------------------------------------------------------------
// softmax over sequence dim per batch (in place on w)
// ---------------------------------------------------------------------------
__global__ __launch_bounds__(256) void seq_softmax_kernel(float* __restrict__ w) {
  __shared__ float red[4];
  const int b = blockIdx.x, t = threadIdx.x;
  const int wave = t >> 6, lane = t & 63;
  float* wb = w + (size_t)b * S_;
  float vals[16];
  float mx = -INFINITY;
#pragma unroll
  for (int i = 0; i < 16; ++i) {
    vals[i] = wb[t + (i << 8)];
    mx = fmaxf(mx, vals[i]);
  }
#pragma unroll
  for (int off = 32; off > 0; off >>= 1) mx = fmaxf(mx, __shfl_xor(mx, off, 64));
  if (lane == 0) red[wave] = mx;
  __syncthreads();
  const float M = fmaxf(fmaxf(red[0], red[1]), fmaxf(red[2], red[3]));
  float sum = 0.f;
#pragma unroll
  for (int i = 0; i < 16; ++i) {
    vals[i] = __expf(vals[i] - M);
    sum += vals[i];
  }
#pragma unroll
  for (int off = 32; off > 0; off >>= 1) sum += __shfl_xor(sum, off, 64);
  __syncthreads();
  if (lane == 0) red[wave] = sum;
  __syncthreads();
  const float inv = 1.0f / (red[0] + red[1] + red[2] + red[3]);
#pragma unroll
  for (int i = 0; i < 16; ++i) wb[t + (i << 8)] = vals[i] * inv;
}

// ---------------------------------------------------------------------------
// out[b,s,:] *= nw[b,s]
// ---------------------------------------------------------------------------
__global__ __launch_bounds__(256) void scale_kernel(
    float* __restrict__ out, const float* __restrict__ nw) {
  const size_t g = (size_t)blockIdx.x * 256 + threadIdx.x;
  float4* o4 = (float4*)out;
  float4 vv = o4[g];
  const float sc = nw[g >> 6];
  vv.x *= sc; vv.y *= sc; vv.z *= sc; vv.w *= sc;
  o4[g] = vv;
}

// ---------------------------------------------------------------------------
extern "C" void kernel_launch(void* const* d_in, const int* in_sizes, int n_in,
                              void* d_out, int out_size, void* d_ws, size_t ws_size,
                              hipStream_t stream) {
  const float* x  = (const float*)d_in[0];
  const float* Wq = (const float*)d_in[1];
  const float* bq = (const float*)d_in[2];
  const float* Wk = (const float*)d_in[3];
  const float* bk = (const float*)d_in[4];
  const float* Wv = (const float*)d_in[5];
  const float* bv = (const float*)d_in[6];
  const float* Wo = (const float*)d_in[7];
  const float* bo = (const float*)d_in[8];
  const float* cv = (const float*)d_in[9];
  float* out = (float*)d_out;

  const size_t N = (size_t)B_ * S_ * D_;  // 8,388,608 elements
  short* qh  = (short*)d_ws;      // [b][s][d] bf16 hi (Q pre-scaled by 1/16)
  short* ql  = qh + N;            // [b][s][d] bf16 lo
  short* kh  = ql + N;            // [b][s][d]
  short* kl  = kh + N;
  short* vth = kl + N;            // [b][d][s]
  short* vtl = vth + N;
  float* ctx = (float*)(vtl + N); // [b][s][d] fp32
  float* w   = ctx + N;           // B*S floats

  proj_split_nat_kernel<<<512, 256, 0, stream>>>(x, Wq, bq, qh, ql, 0.0625f);
  proj_split_nat_kernel<<<512, 256, 0, stream>>>(x, Wk, bk, kh, kl, 1.0f);
  proj_split_t_kernel<<<512, 256, 0, stream>>>(x, Wv, bv, vth, vtl);
  flash_attn_mfma<<<dim3(32, 8), 512, 0, stream>>>(qh, ql, kh, kl, vth, vtl, ctx);
  gemm_bias_kernel<<<512, 256, 0, stream>>>(ctx, Wo, bo, out);
  wdot_kernel<<<8192, 256, 0, stream>>>(out, cv, w);
  seq_softmax_kernel<<<8, 256, 0, stream>>>(w);
  scale_kernel<<<8192, 256, 0, stream>>>(out, w);
}

// Round 2
// 780.147 us; speedup vs baseline: 1.6200x; 1.0131x over previous
//
#include <hip/hip_runtime.h>
#include <math.h>
#include <cstddef>
#include <cstdint>

#define B_ 8
#define S_ 4096
#define D_ 256

typedef __attribute__((ext_vector_type(8))) short short8v;   // 8 bf16 (4 VGPR)
typedef __attribute__((ext_vector_type(4))) short short4v;   // 4 bf16 (8 B)
typedef __attribute__((ext_vector_type(4))) float float4v;   // MFMA C/D

// float -> bf16 (RNE) and back, on bit patterns
__device__ __forceinline__ unsigned short f2bf(float f) {
  unsigned u = __float_as_uint(f);
  return (unsigned short)((u + 0x7FFF + ((u >> 16) & 1)) >> 16);
}
__device__ __forceinline__ float bf2f(unsigned short h) {
  return __uint_as_float((unsigned)h << 16);
}

// ---------------------------------------------------------------------------
// fp32 GEMM (used for Wo): C[M,256] = A @ W + bias, natural layout.
// ---------------------------------------------------------------------------
__global__ __launch_bounds__(256, 2) void gemm_bias_kernel(
    const float* __restrict__ A, const float* __restrict__ W,
    const float* __restrict__ bias, float* __restrict__ C) {
  __shared__ __align__(16) float sA[32 * 68];
  __shared__ __align__(16) float sW[32 * 260];
  const int t  = threadIdx.x;
  const int tx = t & 31;
  const int ty = t >> 5;
  const size_t m0 = (size_t)blockIdx.x * 64;

  float acc[8][8] = {};

  for (int kc = 0; kc < 8; ++kc) {
    const int k0 = kc << 5;
    __syncthreads();
#pragma unroll
    for (int l = 0; l < 2; ++l) {
      const int idx = t + (l << 8);
      const int r = idx >> 3, cf = (idx & 7) << 2;
      const float4 a4 = *(const float4*)(A + (m0 + r) * 256 + k0 + cf);
      sA[(cf + 0) * 68 + r] = a4.x;
      sA[(cf + 1) * 68 + r] = a4.y;
      sA[(cf + 2) * 68 + r] = a4.z;
      sA[(cf + 3) * 68 + r] = a4.w;
    }
#pragma unroll
    for (int l = 0; l < 8; ++l) {
      const int idx = t + (l << 8);
      const int kr = idx >> 6, nc = (idx & 63) << 2;
      *(float4*)&sW[kr * 260 + nc] =
          *(const float4*)(W + (size_t)(k0 + kr) * 256 + nc);
    }
    __syncthreads();
#pragma unroll
    for (int kk = 0; kk < 32; ++kk) {
      const float4 a0 = *(const float4*)&sA[kk * 68 + (ty << 3)];
      const float4 a1 = *(const float4*)&sA[kk * 68 + (ty << 3) + 4];
      const float4 b0 = *(const float4*)&sW[kk * 260 + (tx << 2)];
      const float4 b1 = *(const float4*)&sW[kk * 260 + 128 + (tx << 2)];
      const float av[8] = {a0.x, a0.y, a0.z, a0.w, a1.x, a1.y, a1.z, a1.w};
      const float bv[8] = {b0.x, b0.y, b0.z, b0.w, b1.x, b1.y, b1.z, b1.w};
#pragma unroll
      for (int i = 0; i < 8; ++i)
#pragma unroll
        for (int c = 0; c < 8; ++c) acc[i][c] += av[i] * bv[c];
    }
  }

  const float4 bb0 = *(const float4*)(bias + (tx << 2));
  const float4 bb1 = *(const float4*)(bias + 128 + (tx << 2));
#pragma unroll
  for (int i = 0; i < 8; ++i) {
    float4 o0, o1;
    o0.x = acc[i][0] + bb0.x; o0.y = acc[i][1] + bb0.y;
    o0.z = acc[i][2] + bb0.z; o0.w = acc[i][3] + bb0.w;
    o1.x = acc[i][4] + bb1.x; o1.y = acc[i][5] + bb1.y;
    o1.z = acc[i][6] + bb1.z; o1.w = acc[i][7] + bb1.w;
    float* cp = C + (m0 + (ty << 3) + i) * 256;
    *(float4*)(cp + (tx << 2)) = o0;
    *(float4*)(cp + 128 + (tx << 2)) = o1;
  }
}

// ---------------------------------------------------------------------------
// Projection GEMM -> split-bf16 NATURAL output [b][s][d]: yh + yl (hi/lo).
// scale folded in before the split (Q uses 1/16, K uses 1).
// ---------------------------------------------------------------------------
__global__ __launch_bounds__(256, 2) void proj_split_nat_kernel(
    const float* __restrict__ A, const float* __restrict__ W,
    const float* __restrict__ bias, short* __restrict__ outh,
    short* __restrict__ outl, float scale) {
  __shared__ __align__(16) float sA[32 * 68];
  __shared__ __align__(16) float sW[32 * 260];
  const int t  = threadIdx.x;
  const int tx = t & 31;
  const int ty = t >> 5;
  const size_t m0 = (size_t)blockIdx.x * 64;

  float acc[8][8] = {};

  for (int kc = 0; kc < 8; ++kc) {
    const int k0 = kc << 5;
    __syncthreads();
#pragma unroll
    for (int l = 0; l < 2; ++l) {
      const int idx = t + (l << 8);
      const int r = idx >> 3, cf = (idx & 7) << 2;
      const float4 a4 = *(const float4*)(A + (m0 + r) * 256 + k0 + cf);
      sA[(cf + 0) * 68 + r] = a4.x;
      sA[(cf + 1) * 68 + r] = a4.y;
      sA[(cf + 2) * 68 + r] = a4.z;
      sA[(cf + 3) * 68 + r] = a4.w;
    }
#pragma unroll
    for (int l = 0; l < 8; ++l) {
      const int idx = t + (l << 8);
      const int kr = idx >> 6, nc = (idx & 63) << 2;
      *(float4*)&sW[kr * 260 + nc] =
          *(const float4*)(W + (size_t)(k0 + kr) * 256 + nc);
    }
    __syncthreads();
#pragma unroll
    for (int kk = 0; kk < 32; ++kk) {
      const float4 a0 = *(const float4*)&sA[kk * 68 + (ty << 3)];
      const float4 a1 = *(const float4*)&sA[kk * 68 + (ty << 3) + 4];
      const float4 b0 = *(const float4*)&sW[kk * 260 + (tx << 2)];
      const float4 b1 = *(const float4*)&sW[kk * 260 + 128 + (tx << 2)];
      const float av[8] = {a0.x, a0.y, a0.z, a0.w, a1.x, a1.y, a1.z, a1.w};
      const float bv[8] = {b0.x, b0.y, b0.z, b0.w, b1.x, b1.y, b1.z, b1.w};
#pragma unroll
      for (int i = 0; i < 8; ++i)
#pragma unroll
        for (int c = 0; c < 8; ++c) acc[i][c] += av[i] * bv[c];
    }
  }

  const float4 bb0 = *(const float4*)(bias + (tx << 2));
  const float4 bb1 = *(const float4*)(bias + 128 + (tx << 2));
  const float bb0v[4] = {bb0.x, bb0.y, bb0.z, bb0.w};
  const float bb1v[4] = {bb1.x, bb1.y, bb1.z, bb1.w};
#pragma unroll
  for (int i = 0; i < 8; ++i) {
    const size_t ro = (m0 + (ty << 3) + i) * 256;
    short4v h0, l0, h1, l1;
#pragma unroll
    for (int c = 0; c < 4; ++c) {
      const float y0 = (acc[i][c] + bb0v[c]) * scale;
      const unsigned short hh0 = f2bf(y0);
      h0[c] = (short)hh0; l0[c] = (short)f2bf(y0 - bf2f(hh0));
      const float y1 = (acc[i][4 + c] + bb1v[c]) * scale;
      const unsigned short hh1 = f2bf(y1);
      h1[c] = (short)hh1; l1[c] = (short)f2bf(y1 - bf2f(hh1));
    }
    *(short4v*)(outh + ro + (tx << 2)) = h0;
    *(short4v*)(outl + ro + (tx << 2)) = l0;
    *(short4v*)(outh + ro + 128 + (tx << 2)) = h1;
    *(short4v*)(outl + ro + 128 + (tx << 2)) = l1;
  }
}

// ---------------------------------------------------------------------------
// V projection -> split-bf16 TRANSPOSED output [b][d][s]: vth + vtl.
// ---------------------------------------------------------------------------
__global__ __launch_bounds__(256, 2) void proj_split_t_kernel(
    const float* __restrict__ A, const float* __restrict__ W,
    const float* __restrict__ bias, short* __restrict__ vth,
    short* __restrict__ vtl) {
  __shared__ __align__(16) float sA[32 * 68];
  __shared__ __align__(16) float sW[32 * 260];
  const int t  = threadIdx.x;
  const int tx = t & 31;
  const int ty = t >> 5;
  const size_t m0 = (size_t)blockIdx.x * 64;

  float acc[8][8] = {};

  for (int kc = 0; kc < 8; ++kc) {
    const int k0 = kc << 5;
    __syncthreads();
#pragma unroll
    for (int l = 0; l < 2; ++l) {
      const int idx = t + (l << 8);
      const int r = idx >> 3, cf = (idx & 7) << 2;
      const float4 a4 = *(const float4*)(A + (m0 + r) * 256 + k0 + cf);
      sA[(cf + 0) * 68 + r] = a4.x;
      sA[(cf + 1) * 68 + r] = a4.y;
      sA[(cf + 2) * 68 + r] = a4.z;
      sA[(cf + 3) * 68 + r] = a4.w;
    }
#pragma unroll
    for (int l = 0; l < 8; ++l) {
      const int idx = t + (l << 8);
      const int kr = idx >> 6, nc = (idx & 63) << 2;
      *(float4*)&sW[kr * 260 + nc] =
          *(const float4*)(W + (size_t)(k0 + kr) * 256 + nc);
    }
    __syncthreads();
#pragma unroll
    for (int kk = 0; kk < 32; ++kk) {
      const float4 a0 = *(const float4*)&sA[kk * 68 + (ty << 3)];
      const float4 a1 = *(const float4*)&sA[kk * 68 + (ty << 3) + 4];
      const float4 b0 = *(const float4*)&sW[kk * 260 + (tx << 2)];
      const float4 b1 = *(const float4*)&sW[kk * 260 + 128 + (tx << 2)];
      const float av[8] = {a0.x, a0.y, a0.z, a0.w, a1.x, a1.y, a1.z, a1.w};
      const float bv[8] = {b0.x, b0.y, b0.z, b0.w, b1.x, b1.y, b1.z, b1.w};
#pragma unroll
      for (int i = 0; i < 8; ++i)
#pragma unroll
        for (int c = 0; c < 8; ++c) acc[i][c] += av[i] * bv[c];
    }
  }

  const size_t bD = (size_t)(m0 >> 12) * (D_ * (size_t)S_);
  const int s0r = (int)(m0 & 4095) + (ty << 3);
#pragma unroll
  for (int c = 0; c < 8; ++c) {
    const int n = (c < 4) ? ((tx << 2) + c) : (128 + (tx << 2) + (c - 4));
    const float bn = bias[n];
    short8v h8, l8;
#pragma unroll
    for (int i = 0; i < 8; ++i) {
      const float y = acc[i][c] + bn;
      const unsigned short hh = f2bf(y);
      h8[i] = (short)hh; l8[i] = (short)f2bf(y - bf2f(hh));
    }
    *(short8v*)(vth + bD + (size_t)n * S_ + s0r) = h8;
    *(short8v*)(vtl + bD + (size_t)n * S_ + s0r) = l8;
  }
}

// ---------------------------------------------------------------------------
// MFMA flash attention, split-bf16 (3-term: Ah*Bh + Ah*Bl + Al*Bh).
// R2 STRUCTURE:
//   - Separate sK (33KB) / sV (40KB) LDS arrays (no union) -> the hazard
//     graph needs only TWO barriers per j-iteration:
//       bar1: publishes K(jt); also separates PV(jt-1) reads from V-write(jt)
//       bar2: publishes V(jt); also separates QK(jt) reads from K-write(jt+1)
//   - RAW __builtin_amdgcn_s_barrier() + explicit "s_waitcnt lgkmcnt(0)"
//     fences instead of __syncthreads(): __syncthreads emits
//     s_waitcnt vmcnt(0) before s_barrier, which DRAINED the just-issued
//     prefetch loads (the R1 stall). Raw barriers leave the global
//     prefetches in flight across the barrier; the compiler inserts the
//     vmcnt wait only at the LDS-write use point, ~2000 cycles after issue.
//   - s_setprio(1) around both MFMA clusters (T5).
// Fragment layouts, split-bf16 math, LDS bank patterns unchanged.
// ---------------------------------------------------------------------------
__global__ __launch_bounds__(512, 2) void flash_attn_mfma(
    const short* __restrict__ qh, const short* __restrict__ ql,
    const short* __restrict__ kh, const short* __restrict__ kl,
    const short* __restrict__ vth, const short* __restrict__ vtl,
    float* __restrict__ ctx) {
  __shared__ __align__(16) short sK[16896];    // Kh [32 j][264 pad] @0, Kl @8448
  __shared__ __align__(16) short sV[20480];    // Vth [256 d][40 pad] @0, Vtl @10240
  __shared__ unsigned int sP[8][16][36];       // 18 KB, per-wave P tiles

  const int t    = threadIdx.x;
  const int w    = t >> 6;          // 0..7
  const int lane = t & 63;
  const int m    = lane & 15;
  const int quad = lane >> 4;
  const int q0   = blockIdx.x * 128;
  const int b    = blockIdx.y;
  const size_t sd = (size_t)b * (S_ * (size_t)D_);
  const size_t bD = (size_t)b * (D_ * (size_t)S_);

  // Q A-frags, resident in registers for the whole kernel
  short8v aqh[8], aql[8];
  {
    const size_t row = sd + (size_t)(q0 + 16 * w + m) * D_;
#pragma unroll
    for (int kk = 0; kk < 8; ++kk) {
      const size_t off = row + kk * 32 + quad * 8;
      aqh[kk] = *(const short8v*)(qh + off);
      aql[kk] = *(const short8v*)(ql + off);
    }
  }

  float4v acc[16];
#pragma unroll
  for (int dt = 0; dt < 16; ++dt) acc[dt] = (float4v){0.f, 0.f, 0.f, 0.f};
  float m_i[4], l_i[4];
#pragma unroll
  for (int r = 0; r < 4; ++r) { m_i[r] = -INFINITY; l_i[r] = 0.f; }

  // ---- staging addresses (512 threads) ----
  // K tile [32 j][256 d]: thread covers rows kr0 and 16+kr0, 8-short chunk kc0
  const int kr0 = t >> 5;            // 0..15
  const int kc0 = (t & 31) << 3;     // 0..248
  // V tile [256 d][32 j]: thread covers row vd, chunks vjh and vjh+8
  const int vd  = t >> 1;            // 0..255
  const int vjh = (t & 1) << 4;      // 0 or 16

  // prefetch registers (named scalars -> stay in VGPRs, no dyn index)
  short8v rKh0, rKh1, rKl0, rKl1;
  short8v rVh0, rVh1, rVl0, rVl1;

  // prologue: issue K(0) loads
  {
    const size_t g0 = sd + (size_t)kr0 * D_ + kc0;
    const size_t g1 = sd + (size_t)(16 + kr0) * D_ + kc0;
    rKh0 = *(const short8v*)(kh + g0);
    rKh1 = *(const short8v*)(kh + g1);
    rKl0 = *(const short8v*)(kl + g0);
    rKl1 = *(const short8v*)(kl + g1);
  }

  for (int jt = 0; jt < 128; ++jt) {
    const int j0 = jt << 5;

    // ---- write prefetched K(jt) regs -> LDS (vmcnt wait auto-inserted) ----
    *(short8v*)&sK[kr0 * 264 + kc0]               = rKh0;
    *(short8v*)&sK[(16 + kr0) * 264 + kc0]        = rKh1;
    *(short8v*)&sK[8448 + kr0 * 264 + kc0]        = rKl0;
    *(short8v*)&sK[8448 + (16 + kr0) * 264 + kc0] = rKl1;
    // ---- issue V(jt) global loads (stay in flight across bar1 + QK) ----
    {
      const size_t g = bD + (size_t)vd * S_ + j0 + vjh;
      rVh0 = *(const short8v*)(vth + g);
      rVh1 = *(const short8v*)(vth + g + 8);
      rVl0 = *(const short8v*)(vtl + g);
      rVl1 = *(const short8v*)(vtl + g + 8);
    }
    // bar1: publish K(jt); PV(jt-1) readers are done. NO vmcnt drain.
    asm volatile("s_waitcnt lgkmcnt(0)" ::: "memory");
    __builtin_amdgcn_s_barrier();
    asm volatile("" ::: "memory");

    // ---- scores: 16(q) x 32(j), D in 8 K-steps of 32 ----
    float4v s0 = (float4v){0.f, 0.f, 0.f, 0.f};
    float4v s1 = (float4v){0.f, 0.f, 0.f, 0.f};
    __builtin_amdgcn_s_setprio(1);
#pragma unroll
    for (int kk = 0; kk < 8; ++kk) {
      const int co = kk * 32 + quad * 8;
      const short8v bh0 = *(const short8v*)&sK[m * 264 + co];
      const short8v bl0 = *(const short8v*)&sK[8448 + m * 264 + co];
      const short8v bh1 = *(const short8v*)&sK[(16 + m) * 264 + co];
      const short8v bl1 = *(const short8v*)&sK[8448 + (16 + m) * 264 + co];
      s0 = __builtin_amdgcn_mfma_f32_16x16x32_bf16(aqh[kk], bh0, s0, 0, 0, 0);
      s0 = __builtin_amdgcn_mfma_f32_16x16x32_bf16(aqh[kk], bl0, s0, 0, 0, 0);
      s0 = __builtin_amdgcn_mfma_f32_16x16x32_bf16(aql[kk], bh0, s0, 0, 0, 0);
      s1 = __builtin_amdgcn_mfma_f32_16x16x32_bf16(aqh[kk], bh1, s1, 0, 0, 0);
      s1 = __builtin_amdgcn_mfma_f32_16x16x32_bf16(aqh[kk], bl1, s1, 0, 0, 0);
      s1 = __builtin_amdgcn_mfma_f32_16x16x32_bf16(aql[kk], bh1, s1, 0, 0, 0);
    }
    __builtin_amdgcn_s_setprio(0);

    // ---- online softmax (row r of this wave's tile = quad*4 + r) ----
    float alpha[4], pr0[4], pr1[4];
#pragma unroll
    for (int r = 0; r < 4; ++r) {
      float mx = fmaxf(s0[r], s1[r]);
      mx = fmaxf(mx, __shfl_xor(mx, 1, 64));
      mx = fmaxf(mx, __shfl_xor(mx, 2, 64));
      mx = fmaxf(mx, __shfl_xor(mx, 4, 64));
      mx = fmaxf(mx, __shfl_xor(mx, 8, 64));
      const float mnew = fmaxf(m_i[r], mx);
      alpha[r] = __expf(m_i[r] - mnew);
      m_i[r] = mnew;
      const float p0 = __expf(s0[r] - mnew);
      const float p1 = __expf(s1[r] - mnew);
      float rs = p0 + p1;
      rs += __shfl_xor(rs, 1, 64);
      rs += __shfl_xor(rs, 2, 64);
      rs += __shfl_xor(rs, 4, 64);
      rs += __shfl_xor(rs, 8, 64);
      l_i[r] = l_i[r] * alpha[r] + rs;
      pr0[r] = p0; pr1[r] = p1;
    }

    // ---- write split P to per-wave LDS (wave-private; no barrier needed) ----
#pragma unroll
    for (int r = 0; r < 4; ++r) {
      {
        const float p = pr0[r];
        const unsigned short hh = f2bf(p);
        const unsigned short ll = f2bf(p - bf2f(hh));
        sP[w][quad * 4 + r][m] = ((unsigned)hh << 16) | (unsigned)ll;
      }
      {
        const float p = pr1[r];
        const unsigned short hh = f2bf(p);
        const unsigned short ll = f2bf(p - bf2f(hh));
        sP[w][quad * 4 + r][16 + m] = ((unsigned)hh << 16) | (unsigned)ll;
      }
    }

    // ---- rescale ctx accumulators ----
#pragma unroll
    for (int dt = 0; dt < 16; ++dt)
#pragma unroll
      for (int r = 0; r < 4; ++r) acc[dt][r] *= alpha[r];

    // ---- write prefetched V(jt) regs -> LDS (vmcnt wait lands HERE,
    //      ~2000 cycles after issue -> latency hidden under QK+softmax) ----
    *(short8v*)&sV[vd * 40 + vjh]               = rVh0;
    *(short8v*)&sV[vd * 40 + vjh + 8]           = rVh1;
    *(short8v*)&sV[10240 + vd * 40 + vjh]       = rVl0;
    *(short8v*)&sV[10240 + vd * 40 + vjh + 8]   = rVl1;
    // ---- issue K(jt+1) global loads (in flight across bar2 + PV) ----
    if (jt < 127) {
      const int j0n = j0 + 32;
      const size_t g0 = sd + (size_t)(j0n + kr0) * D_ + kc0;
      const size_t g1 = sd + (size_t)(j0n + 16 + kr0) * D_ + kc0;
      rKh0 = *(const short8v*)(kh + g0);
      rKh1 = *(const short8v*)(kh + g1);
      rKl0 = *(const short8v*)(kl + g0);
      rKl1 = *(const short8v*)(kl + g1);
    }
    // bar2: publish V(jt) + this wave's sP; QK(jt) readers of sK are done.
    asm volatile("s_waitcnt lgkmcnt(0)" ::: "memory");
    __builtin_amdgcn_s_barrier();
    asm volatile("" ::: "memory");

    // ---- P A-frag: read back in A-layout, unpack hi/lo ----
    short8v ph, pl;
    {
      const uint4 pa = *(const uint4*)&sP[w][m][quad * 8];
      const uint4 pb = *(const uint4*)&sP[w][m][quad * 8 + 4];
      ph[0] = (short)(pa.x >> 16); pl[0] = (short)(pa.x & 0xffff);
      ph[1] = (short)(pa.y >> 16); pl[1] = (short)(pa.y & 0xffff);
      ph[2] = (short)(pa.z >> 16); pl[2] = (short)(pa.z & 0xffff);
      ph[3] = (short)(pa.w >> 16); pl[3] = (short)(pa.w & 0xffff);
      ph[4] = (short)(pb.x >> 16); pl[4] = (short)(pb.x & 0xffff);
      ph[5] = (short)(pb.y >> 16); pl[5] = (short)(pb.y & 0xffff);
      ph[6] = (short)(pb.z >> 16); pl[6] = (short)(pb.z & 0xffff);
      ph[7] = (short)(pb.w >> 16); pl[7] = (short)(pb.w & 0xffff);
    }

    // ---- PV: ctx[16 q][256 d] += P[16 q][32 j] @ V[32 j][256 d] ----
    __builtin_amdgcn_s_setprio(1);
#pragma unroll
    for (int dt = 0; dt < 16; ++dt) {
      const int vr = (dt * 16 + m) * 40 + quad * 8;
      const short8v bh = *(const short8v*)&sV[vr];
      const short8v bl = *(const short8v*)&sV[10240 + vr];
      acc[dt] = __builtin_amdgcn_mfma_f32_16x16x32_bf16(ph, bh, acc[dt], 0, 0, 0);
      acc[dt] = __builtin_amdgcn_mfma_f32_16x16x32_bf16(ph, bl, acc[dt], 0, 0, 0);
      acc[dt] = __builtin_amdgcn_mfma_f32_16x16x32_bf16(pl, bh, acc[dt], 0, 0, 0);
    }
    __builtin_amdgcn_s_setprio(0);
  }

  // ---- finalize: divide by l, store ctx (C-layout scatter, 64B granules) ----
#pragma unroll
  for (int r = 0; r < 4; ++r) {
    const float inv = 1.0f / l_i[r];
    float* cp = ctx + sd + (size_t)(q0 + 16 * w + quad * 4 + r) * D_ + m;
#pragma unroll
    for (int dt = 0; dt < 16; ++dt) cp[dt * 16] = acc[dt][r] * inv;
  }
}

// ---------------------------------------------------------------------------
// w[row] = dot(logits[row,:], cv)
// ---------------------------------------------------------------------------
__global__ __launch_bounds__(256) void wdot_kernel(
    const float* __restrict__ logits, const float* __restrict__ cv,
    float* __restrict__ w) {
  const int t    = threadIdx.x;
  const int wave = t >> 6, lane = t & 63;
  const size_t row = (size_t)blockIdx.x * 4 + wave;
  const float4 l4 = *(const float4*)(logits + row * 256 + (lane << 2));
  const float4 c4 = *(const float4*)(cv + (lane << 2));
  float p = l4.x * c4.x + l4.y * c4.y + l4.z * c4.z + l4.w * c4.w;
#pragma unroll
  for (int off = 32; off > 0; off >>= 1) p += __shfl_down(p, off, 64);
  if (lane == 0) w[row] = p;
}

// ---------------------------------------------------------------------------
// softmax over sequence dim per batch (in place on w)
// ---------------------------------------------------------------------------
__global__ __launch_bounds__(256) void seq_softmax_kernel(float* __restrict__ w) {
  __shared__ float red[4];
  const int b = blockIdx.x, t = threadIdx.x;
  const int wave = t >> 6, lane = t & 63;
  float* wb = w + (size_t)b * S_;
  float vals[16];
  float mx = -INFINITY;
#pragma unroll
  for (int i = 0; i < 16; ++i) {
    vals[i] = wb[t + (i << 8)];
    mx = fmaxf(mx, vals[i]);
  }
#pragma unroll
  for (int off = 32; off > 0; off >>= 1) mx = fmaxf(mx, __shfl_xor(mx, off, 64));
  if (lane == 0) red[wave] = mx;
  __syncthreads();
  const float M = fmaxf(fmaxf(red[0], red[1]), fmaxf(red[2], red[3]));
  float sum = 0.f;
#pragma unroll
  for (int i = 0; i < 16; ++i) {
    vals[i] = __expf(vals[i] - M);
    sum += vals[i];
  }
#pragma unroll
  for (int off = 32; off > 0; off >>= 1) sum += __shfl_xor(sum, off, 64);
  __syncthreads();
  if (lane == 0) red[wave] = sum;
  __syncthreads();
  const float inv = 1.0f / (red[0] + red[1] + red[2] + red[3]);
#pragma unroll
  for (int i = 0; i < 16; ++i) wb[t + (i << 8)] = vals[i] * inv;
}

// ---------------------------------------------------------------------------
// out[b,s,:] *= nw[b,s]
// ---------------------------------------------------------------------------
__global__ __launch_bounds__(256) void scale_kernel(
    float* __restrict__ out, const float* __restrict__ nw) {
  const size_t g = (size_t)blockIdx.x * 256 + threadIdx.x;
  float4* o4 = (float4*)out;
  float4 vv = o4[g];
  const float sc = nw[g >> 6];
  vv.x *= sc; vv.y *= sc; vv.z *= sc; vv.w *= sc;
  o4[g] = vv;
}

// ---------------------------------------------------------------------------
extern "C" void kernel_launch(void* const* d_in, const int* in_sizes, int n_in,
                              void* d_out, int out_size, void* d_ws, size_t ws_size,
                              hipStream_t stream) {
  const float* x  = (const float*)d_in[0];
  const float* Wq = (const float*)d_in[1];
  const float* bq = (const float*)d_in[2];
  const float* Wk = (const float*)d_in[3];
  const float* bk = (const float*)d_in[4];
  const float* Wv = (const float*)d_in[5];
  const float* bv = (const float*)d_in[6];
  const float* Wo = (const float*)d_in[7];
  const float* bo = (const float*)d_in[8];
  const float* cv = (const float*)d_in[9];
  float* out = (float*)d_out;

  const size_t N = (size_t)B_ * S_ * D_;  // 8,388,608 elements
  short* qh  = (short*)d_ws;      // [b][s][d] bf16 hi (Q pre-scaled by 1/16)
  short* ql  = qh + N;            // [b][s][d] bf16 lo
  short* kh  = ql + N;            // [b][s][d]
  short* kl  = kh + N;
  short* vth = kl + N;            // [b][d][s]
  short* vtl = vth + N;
  float* ctx = (float*)(vtl + N); // [b][s][d] fp32
  float* w   = ctx + N;           // B*S floats

  proj_split_nat_kernel<<<512, 256, 0, stream>>>(x, Wq, bq, qh, ql, 0.0625f);
  proj_split_nat_kernel<<<512, 256, 0, stream>>>(x, Wk, bk, kh, kl, 1.0f);
  proj_split_t_kernel<<<512, 256, 0, stream>>>(x, Wv, bv, vth, vtl);
  flash_attn_mfma<<<dim3(32, 8), 512, 0, stream>>>(qh, ql, kh, kl, vth, vtl, ctx);
  gemm_bias_kernel<<<512, 256, 0, stream>>>(ctx, Wo, bo, out);
  wdot_kernel<<<8192, 256, 0, stream>>>(out, cv, w);
  seq_softmax_kernel<<<8, 256, 0, stream>>>(w);
  scale_kernel<<<8192, 256, 0, stream>>>(out, w);
}